// Round 13
// baseline (321.951 us; speedup 1.0000x reference)
//
#include <hip/hip_runtime.h>
#include <hip/hip_bf16.h>
#include <float.h>

#define Npts 16384
#define Dims 64
#define Oout 128
#define KNN  10
#define LC   12                      // per-stream coarse list
#define NR   16                      // VIRTUAL ranges (8 physical x 2 half-streams)
#define RLEN 2048                    // physical range length
#define NCG  (RLEN / 32)             // 64 cand-groups of 32
#define QW   39                      // queue words per lane (odd: coprime w/ 32 banks)

typedef __attribute__((ext_vector_type(8))) short s16x8;
typedef __attribute__((ext_vector_type(16))) float f32x16;

__device__ __forceinline__ unsigned short f2bf(float f) {
    unsigned u = __float_as_uint(f);
    return (unsigned short)((u + 0x7FFFu + ((u >> 16) & 1u)) >> 16);
}
__device__ __forceinline__ float bf2f(unsigned short b) {
    return __uint_as_float(((unsigned)b) << 16);
}
// bf16 * (-2): flip sign, exp+1 (exact; zero/denorm handled)
__device__ __forceinline__ short neg2(short hs) {
    unsigned short h = (unsigned short)hs;
    unsigned short m = (unsigned short)(h ^ 0x8000u);
    return (short)(((h & 0x7F80u) == 0) ? m : (unsigned short)(m + 0x0080u));
}

__device__ __forceinline__ void insertL(float (&bd)[LC], int (&bi)[LC], float s, int j) {
    if (s < bd[LC - 1]) {
#pragma unroll
        for (int k = LC - 1; k >= 1; --k) {
            bool up = bd[k - 1] > s;
            float nd = up ? bd[k - 1] : ((bd[k] > s) ? s : bd[k]);
            int   ni = up ? bi[k - 1] : ((bd[k] > s) ? j : bi[k]);
            bd[k] = nd; bi[k] = ni;
        }
        bool u0 = bd[0] > s;
        bi[0] = u0 ? j : bi[0];
        bd[0] = u0 ? s : bd[0];
    }
}

// ------- k_tr: transpose + bf16 hi split + sq-aux (bf16 hi/lo) -------
__global__ __launch_bounds__(256) void k_tr(const float* __restrict__ x,
                                            float* __restrict__ ptsT,
                                            unsigned short* __restrict__ xh,
                                            unsigned short* __restrict__ axh) {
    __shared__ float tile[64][65];
    const int b = blockIdx.x;
    for (int i = threadIdx.x; i < 64 * 64; i += 256) {
        int d = i >> 6, p = i & 63;
        tile[d][p] = x[d * Npts + b * 64 + p];
    }
    __syncthreads();
    for (int i = threadIdx.x; i < 64 * 64; i += 256) {
        int p = i >> 6, d = i & 63;
        float v = tile[d][p];
        ptsT[(b * 64 + p) * 64 + d] = v;
        xh[(b * 64 + p) * 64 + d] = (unsigned short)f2bf(v);
    }
    __syncthreads();
    if (threadIdx.x < 64) {
        int p = threadIdx.x;
        float a = 0.f;
#pragma unroll
        for (int d = 0; d < 64; ++d) { float v = tile[d][p]; a = fmaf(v, v, a); }
        unsigned short h = f2bf(a);
        unsigned short lo = f2bf(a - bf2f(h));
        s16x8 v8 = {(short)h, (short)lo, 0, 0, 0, 0, 0, 0};
        *(s16x8*)(axh + (size_t)(b * 64 + p) * 8) = v8;
    }
}

// ------- k_y: y[n][o] = W[o]·pts[n] + b[o], LDS-tiled -------
__global__ __launch_bounds__(256) void k_y(const float* __restrict__ ptsT,
                                           const float* __restrict__ W,
                                           const float* __restrict__ bias,
                                           float* __restrict__ y) {
    __shared__ float wsh[128][65];
    __shared__ float xs[8][64];
    const int t = threadIdx.x;
    const int nb = blockIdx.x * 8;
    for (int i = t; i < 128 * 64; i += 256) {
        int o = i >> 6, d = i & 63;
        wsh[o][d] = W[i];
    }
    for (int i = t; i < 8 * 64; i += 256) {
        int n8 = i >> 6, d = i & 63;
        xs[n8][d] = ptsT[(nb + n8) * 64 + d];
    }
    __syncthreads();
    const int o = t & 127, nn = t >> 7;
    float a0 = bias[o], a1 = a0, a2 = a0, a3 = a0;
#pragma unroll
    for (int d = 0; d < 64; ++d) {
        float wv = wsh[o][d];
        a0 = fmaf(xs[nn * 4 + 0][d], wv, a0);
        a1 = fmaf(xs[nn * 4 + 1][d], wv, a1);
        a2 = fmaf(xs[nn * 4 + 2][d], wv, a2);
        a3 = fmaf(xs[nn * 4 + 3][d], wv, a3);
    }
    y[(nb + nn * 4 + 0) * 128 + o] = a0;
    y[(nb + nn * 4 + 1) * 128 + o] = a1;
    y[(nb + nn * 4 + 2) * 128 + o] = a2;
    y[(nb + nn * 4 + 3) * 128 + o] = a3;
}

// ------- k_knn: 32x32 MFMA, scores born in owning lane; no LDS bounce -------
// grid: 512 qgroups x 2 range-pairs; block 256 = 4 waves.
// Wave w: physical range (rp*4+w) of 2048 cands, for the block's 32 queries.
// Swapped mfma: D[cand][query]; lane l -> query l&31, 16 cand-rows
// row = (reg&3) + 8*(reg>>2) + 4*(l>>5)  [m74/m101 layout].
__global__ __launch_bounds__(256, 4) void k_knn(const unsigned short* __restrict__ xh,
                                                const unsigned short* __restrict__ axh,
                                                float* __restrict__ outS,
                                                unsigned short* __restrict__ outI) {
    __shared__ unsigned qq[4][64][QW];     // 39936 B -> 4 blocks/CU

    const int t    = threadIdx.x;
    const int w    = __builtin_amdgcn_readfirstlane(t >> 6);
    const int l    = t & 63;
    const int q31  = l & 31;               // query col (B) AND cand row (A)
    const int hb   = l >> 5;               // half-stream select
    const int hb4  = hb * 4;
    const int qblk = blockIdx.x >> 1;      // 0..511
    const int rp   = blockIdx.x & 1;
    const int range = rp * 4 + w;          // physical 0..7
    const int rbase = range * RLEN;
    const unsigned short* xr  = xh + (size_t)rbase * 64;
    const unsigned short* axr = axh + (size_t)rbase * 8;
    const int q = qblk * 32 + q31;         // lane's own query

    // B-frags: query q, k = s*16 + hb*8 + e, scaled by -2 (exact in bf16)
    s16x8 B0, B1, B2q, B3;
    {
        const unsigned short* qp = xh + (size_t)q * 64 + hb * 8;
        s16x8 h0 = *(const s16x8*)qp;
        s16x8 h1 = *(const s16x8*)(qp + 16);
        s16x8 h2 = *(const s16x8*)(qp + 32);
        s16x8 h3 = *(const s16x8*)(qp + 48);
#pragma unroll
        for (int e = 0; e < 8; ++e) {
            B0[e] = neg2(h0[e]); B1[e] = neg2(h1[e]);
            B2q[e] = neg2(h2[e]); B3[e] = neg2(h3[e]);
        }
    }
    // sq-fold B-frag: B[*][k] = 1.0 for k in {0,1}; k=0..7 live on hb==0 lanes
    s16x8 bs = {0, 0, 0, 0, 0, 0, 0, 0};
    if (hb == 0) { bs[0] = (short)0x3F80; bs[1] = (short)0x3F80; }

    float bd[LC]; int bi[LC];
#pragma unroll
    for (int k = 0; k < LC; ++k) { bd[k] = FLT_MAX; bi[k] = -1; }
    float tau = FLT_MAX;
    int myq = 0;
    unsigned* myqq = &qq[w][l][0];

    for (int ci = 0; ci < NCG; ++ci) {
        const int cb = ci * 32;
        // A-frags: cand row (cb+q31), k = s*16 + hb*8 + e; sq-aux likewise
        const unsigned short* ap = xr + (size_t)(cb + q31) * 64 + hb * 8;
        const s16x8 A0 = *(const s16x8*)ap;
        const s16x8 A1 = *(const s16x8*)(ap + 16);
        const s16x8 A2 = *(const s16x8*)(ap + 32);
        const s16x8 A3 = *(const s16x8*)(ap + 48);
        const s16x8 Aq = *(const s16x8*)(axr + (size_t)(cb + q31) * 8);

        f32x16 acc = {0.f};
        acc = __builtin_amdgcn_mfma_f32_32x32x16_bf16(A0, B0, acc, 0, 0, 0);
        acc = __builtin_amdgcn_mfma_f32_32x32x16_bf16(A1, B1, acc, 0, 0, 0);
        acc = __builtin_amdgcn_mfma_f32_32x32x16_bf16(A2, B2q, acc, 0, 0, 0);
        acc = __builtin_amdgcn_mfma_f32_32x32x16_bf16(A3, B3, acc, 0, 0, 0);
        acc = __builtin_amdgcn_mfma_f32_32x32x16_bf16(Aq, bs, acc, 0, 0, 0);
        // acc[r] = sq_c - 2*q.c  for cand c = cb + (r&3) + 8*(r>>2) + hb4

        const unsigned pb = (unsigned)(ci * 16);
#pragma unroll
        for (int r = 0; r < 16; ++r) {
            const float s = acc[r];
            unsigned e = (__float_as_uint(s) & ~1023u) | (pb + r);
            myqq[myq] = e;                 // unconditional write (pad-safe)
            myq += (s < tau) ? 1 : 0;      // conditional bump
        }

        // wave-uniform drain (invariant: myq<=23 at entry; max write idx 38 < 39)
        if (__any(myq > QW - 16)) {
            for (int i = 0; i < myq; ++i) {
                unsigned e = myqq[i];
                int lo = (int)(e & 1023u);
                int r  = lo & 15;
                int c  = rbase + (lo >> 4) * 32 + (r & 3) + 8 * (r >> 2) + hb4;
                insertL(bd, bi, __uint_as_float(e & ~1023u), c);
            }
            myq = 0;
            tau = bd[LC - 1];
        }
    }

    if (__any(myq != 0)) {
        for (int i = 0; i < myq; ++i) {
            unsigned e = myqq[i];
            int lo = (int)(e & 1023u);
            int r  = lo & 15;
            int c  = rbase + (lo >> 4) * 32 + (r & 3) + 8 * (r >> 2) + hb4;
            insertL(bd, bi, __uint_as_float(e & ~1023u), c);
        }
    }

    // write this (virtual-range, query) sorted top-12
    const int vr = range * 2 + hb;         // 0..15 virtual ranges
    float* os = outS + ((size_t)vr * Npts + q) * LC;
    unsigned short* oi = outI + ((size_t)vr * Npts + q) * LC;
#pragma unroll
    for (int k = 0; k < LC; ++k) {
        os[k] = bd[k];
        oi[k] = (unsigned short)bi[k];
    }
}

// ------- k_out: 192 coarse -> top24 (2-phase rank) -> fp64 top10 -> gather-max -------
__global__ __launch_bounds__(192) void k_out(const float* __restrict__ y,
                                             const float* __restrict__ ptsT,
                                             const float* __restrict__ outS,
                                             const unsigned short* __restrict__ outI,
                                             float* __restrict__ out) {
    __shared__ float  sc[NR * LC];
    __shared__ int    ix[NR * LC];
    __shared__ float  s2[96];
    __shared__ int    i2[96];
    __shared__ int    c24[24];
    __shared__ double d2s[24];
    __shared__ int    ci[24];
    __shared__ __align__(16) float qs[Dims];
    __shared__ int    nb[KNN];

    const int n = blockIdx.x;
    const int t = threadIdx.x;

    if (t < Dims) qs[t] = ptsT[(size_t)n * Dims + t];
    {
        const int r = t / LC, k = t - r * LC;   // t < 192 = NR*LC
        sc[t] = outS[((size_t)r * Npts + n) * LC + k];
        ix[t] = (int)outI[((size_t)r * Npts + n) * LC + k];
    }
    __syncthreads();

    // phase 1: rank within group of 48, keep top-24 of each (4 groups -> 96)
    {
        const int gb = (t / 48) * 48;
        const float v = sc[t]; const int vi = ix[t];
        int rk = 0;
        for (int c = 0; c < 48; ++c) {
            float oc = sc[gb + c]; int oi = ix[gb + c];
            rk += (oc < v || (oc == v && oi < vi)) ? 1 : 0;
        }
        if (rk < 24) { s2[(t / 48) * 24 + rk] = v; i2[(t / 48) * 24 + rk] = vi; }
    }
    __syncthreads();

    // phase 2: 96 -> coarse top-24
    if (t < 96) {
        const float v = s2[t]; const int vi = i2[t];
        int rk = 0;
        for (int c = 0; c < 96; ++c)
            rk += (s2[c] < v || (s2[c] == v && i2[c] < vi)) ? 1 : 0;
        if (rk < 24) c24[rk] = vi;
    }
    __syncthreads();

    // exact fp64 d2 for 24 candidates
    if (t < 24) {
        const int j = c24[t];
        double acc = 0.0;
#pragma unroll
        for (int d4 = 0; d4 < Dims / 4; ++d4) {
            const float4 pv = *(const float4*)&ptsT[(size_t)j * Dims + d4 * 4];
            const float4 qv = *(const float4*)&qs[d4 * 4];
            double e0 = (double)qv.x - (double)pv.x;
            double e1 = (double)qv.y - (double)pv.y;
            double e2 = (double)qv.z - (double)pv.z;
            double e3 = (double)qv.w - (double)pv.w;
            acc = fma(e0, e0, acc); acc = fma(e1, e1, acc);
            acc = fma(e2, e2, acc); acc = fma(e3, e3, acc);
        }
        d2s[t] = acc; ci[t] = j;
    }
    __syncthreads();

    // exact top-10 by (d2, idx)
    if (t < 24) {
        const double dv = d2s[t]; const int ji = ci[t];
        int rk = 0;
        for (int c = 0; c < 24; ++c)
            rk += (d2s[c] < dv || (d2s[c] == dv && ci[c] < ji)) ? 1 : 0;
        if (rk < KNN) nb[rk] = ji;
    }
    __syncthreads();

    if (t < Oout) {
        float m = -FLT_MAX;
#pragma unroll
        for (int k = 0; k < KNN; ++k)
            m = fmaxf(m, y[(size_t)nb[k] * Oout + t]);
        out[(size_t)n * Oout + t] = m;
    }
}

// ---------------- launcher ----------------
extern "C" void kernel_launch(void* const* d_in, const int* in_sizes, int n_in,
                              void* d_out, int out_size, void* d_ws, size_t ws_size,
                              hipStream_t stream) {
    const float* x = (const float*)d_in[0];   // (1, 64, 16384)
    const float* W = (const float*)d_in[1];   // (128, 64)
    const float* b = (const float*)d_in[2];   // (128,)
    float* out = (float*)d_out;

    float* ws   = (float*)d_ws;
    float* ptsT = ws;                                        // N*D          (4 MB)
    float* y    = ptsT + (size_t)Npts * Dims;                // N*O          (8 MB)
    unsigned short* xh  = (unsigned short*)(y + (size_t)Npts * Oout); // N*D bf16 (2 MB)
    unsigned short* axh = xh + (size_t)Npts * Dims;          // N*8 bf16     (256 KB)
    float* outS = (float*)(axh + (size_t)Npts * 8);          // NR*N*LC f32  (12 MB)
    unsigned short* outI = (unsigned short*)(outS + (size_t)NR * Npts * LC); // (6 MB)

    k_tr <<<Npts / 64, 256, 0, stream>>>(x, ptsT, xh, axh);
    k_y  <<<Npts / 8, 256, 0, stream>>>(ptsT, W, b, y);
    k_knn<<<1024, 256, 0, stream>>>(xh, axh, outS, outI);
    k_out<<<Npts, 192, 0, stream>>>(y, ptsT, outS, outI, out);
}

// Round 14
// 308.538 us; speedup vs baseline: 1.0435x; 1.0435x over previous
//
#include <hip/hip_runtime.h>
#include <hip/hip_bf16.h>
#include <float.h>

#define Npts 16384
#define Dims 64
#define Oout 128
#define KNN  10
#define LC   12                      // per-stream coarse list
#define NR   16                      // VIRTUAL ranges (8 physical x 2 half-streams)
#define RLEN 2048                    // physical range length
#define NCG  (RLEN / 32)             // 64 cand-groups of 32
#define QW   39                      // queue slots per lane

typedef __attribute__((ext_vector_type(8))) short s16x8;
typedef __attribute__((ext_vector_type(16))) float f32x16;

__device__ __forceinline__ unsigned short f2bf(float f) {
    unsigned u = __float_as_uint(f);
    return (unsigned short)((u + 0x7FFFu + ((u >> 16) & 1u)) >> 16);
}
__device__ __forceinline__ float bf2f(unsigned short b) {
    return __uint_as_float(((unsigned)b) << 16);
}
// bf16 * (-2): flip sign, exp+1 (exact; zero/denorm handled)
__device__ __forceinline__ short neg2(short hs) {
    unsigned short h = (unsigned short)hs;
    unsigned short m = (unsigned short)(h ^ 0x8000u);
    return (short)(((h & 0x7F80u) == 0) ? m : (unsigned short)(m + 0x0080u));
}

__device__ __forceinline__ void insertL(float (&bd)[LC], int (&bi)[LC], float s, int j) {
    if (s < bd[LC - 1]) {
#pragma unroll
        for (int k = LC - 1; k >= 1; --k) {
            bool up = bd[k - 1] > s;
            float nd = up ? bd[k - 1] : ((bd[k] > s) ? s : bd[k]);
            int   ni = up ? bi[k - 1] : ((bd[k] > s) ? j : bi[k]);
            bd[k] = nd; bi[k] = ni;
        }
        bool u0 = bd[0] > s;
        bi[0] = u0 ? j : bi[0];
        bd[0] = u0 ? s : bd[0];
    }
}

// ------- k_tr: transpose + bf16 hi split + sq-aux (bf16 hi/lo) -------
__global__ __launch_bounds__(256) void k_tr(const float* __restrict__ x,
                                            float* __restrict__ ptsT,
                                            unsigned short* __restrict__ xh,
                                            unsigned short* __restrict__ axh) {
    __shared__ float tile[64][65];
    const int b = blockIdx.x;
    for (int i = threadIdx.x; i < 64 * 64; i += 256) {
        int d = i >> 6, p = i & 63;
        tile[d][p] = x[d * Npts + b * 64 + p];
    }
    __syncthreads();
    for (int i = threadIdx.x; i < 64 * 64; i += 256) {
        int p = i >> 6, d = i & 63;
        float v = tile[d][p];
        ptsT[(b * 64 + p) * 64 + d] = v;
        xh[(b * 64 + p) * 64 + d] = (unsigned short)f2bf(v);
    }
    __syncthreads();
    if (threadIdx.x < 64) {
        int p = threadIdx.x;
        float a = 0.f;
#pragma unroll
        for (int d = 0; d < 64; ++d) { float v = tile[d][p]; a = fmaf(v, v, a); }
        unsigned short h = f2bf(a);
        unsigned short lo = f2bf(a - bf2f(h));
        s16x8 v8 = {(short)h, (short)lo, 0, 0, 0, 0, 0, 0};
        *(s16x8*)(axh + (size_t)(b * 64 + p) * 8) = v8;
    }
}

// ------- k_y: y[n][o] = W[o]·pts[n] + b[o], LDS-tiled -------
__global__ __launch_bounds__(256) void k_y(const float* __restrict__ ptsT,
                                           const float* __restrict__ W,
                                           const float* __restrict__ bias,
                                           float* __restrict__ y) {
    __shared__ float wsh[128][65];
    __shared__ float xs[8][64];
    const int t = threadIdx.x;
    const int nb = blockIdx.x * 8;
    for (int i = t; i < 128 * 64; i += 256) {
        int o = i >> 6, d = i & 63;
        wsh[o][d] = W[i];
    }
    for (int i = t; i < 8 * 64; i += 256) {
        int n8 = i >> 6, d = i & 63;
        xs[n8][d] = ptsT[(nb + n8) * 64 + d];
    }
    __syncthreads();
    const int o = t & 127, nn = t >> 7;
    float a0 = bias[o], a1 = a0, a2 = a0, a3 = a0;
#pragma unroll
    for (int d = 0; d < 64; ++d) {
        float wv = wsh[o][d];
        a0 = fmaf(xs[nn * 4 + 0][d], wv, a0);
        a1 = fmaf(xs[nn * 4 + 1][d], wv, a1);
        a2 = fmaf(xs[nn * 4 + 2][d], wv, a2);
        a3 = fmaf(xs[nn * 4 + 3][d], wv, a3);
    }
    y[(nb + nn * 4 + 0) * 128 + o] = a0;
    y[(nb + nn * 4 + 1) * 128 + o] = a1;
    y[(nb + nn * 4 + 2) * 128 + o] = a2;
    y[(nb + nn * 4 + 3) * 128 + o] = a3;
}

// ------- k_knn: 32x32 MFMA x2 independent chains; bank-aligned queues -------
// grid: 512 qgroups x 2 range-pairs; block 256 = 4 waves.
// Wave w: physical range (rp*4+w) of 2048 cands, for the block's 32 queries.
// Swapped mfma: D[cand][query]; lane l -> query l&31, 16 cand-rows
// row = (reg&3) + 8*(reg>>2) + 4*(l>>5)  [m74/m101 layout].
__global__ __launch_bounds__(256, 4) void k_knn(const unsigned short* __restrict__ xh,
                                                const unsigned short* __restrict__ axh,
                                                float* __restrict__ outS,
                                                unsigned short* __restrict__ outI) {
    __shared__ unsigned qq[4][QW][64];     // 39936 B; bank = lane mod 32 (2-way free)

    const int t    = threadIdx.x;
    const int w    = __builtin_amdgcn_readfirstlane(t >> 6);
    const int l    = t & 63;
    const int q31  = l & 31;               // query col (B) AND cand row (A)
    const int hb   = l >> 5;               // half-stream select
    const int hb4  = hb * 4;
    const int qblk = blockIdx.x >> 1;      // 0..511
    const int rp   = blockIdx.x & 1;
    const int range = rp * 4 + w;          // physical 0..7
    const int rbase = range * RLEN;
    const unsigned short* xr  = xh + (size_t)rbase * 64;
    const unsigned short* axr = axh + (size_t)rbase * 8;
    const int q = qblk * 32 + q31;         // lane's own query

    // B-frags: query q, k = s*16 + hb*8 + e, scaled by -2 (exact in bf16)
    s16x8 B0, B1, B2q, B3;
    {
        const unsigned short* qp = xh + (size_t)q * 64 + hb * 8;
        s16x8 h0 = *(const s16x8*)qp;
        s16x8 h1 = *(const s16x8*)(qp + 16);
        s16x8 h2 = *(const s16x8*)(qp + 32);
        s16x8 h3 = *(const s16x8*)(qp + 48);
#pragma unroll
        for (int e = 0; e < 8; ++e) {
            B0[e] = neg2(h0[e]); B1[e] = neg2(h1[e]);
            B2q[e] = neg2(h2[e]); B3[e] = neg2(h3[e]);
        }
    }
    // sq-fold B-frag: B[*][k] = 1.0 for k in {0,1}; k=0..7 live on hb==0 lanes
    s16x8 bs = {0, 0, 0, 0, 0, 0, 0, 0};
    if (hb == 0) { bs[0] = (short)0x3F80; bs[1] = (short)0x3F80; }

    float bd[LC]; int bi[LC];
#pragma unroll
    for (int k = 0; k < LC; ++k) { bd[k] = FLT_MAX; bi[k] = -1; }
    float tau = FLT_MAX;
    int myq = 0;
    unsigned* myqq = &qq[w][0][l];         // slot i at myqq[i*64]

    for (int ci = 0; ci < NCG; ci += 2) {
        const int cb0 = ci * 32;
        const int cb1 = cb0 + 32;
        // A-frags for BOTH groups (independent chains)
        const unsigned short* apA = xr + (size_t)(cb0 + q31) * 64 + hb * 8;
        const unsigned short* apB = xr + (size_t)(cb1 + q31) * 64 + hb * 8;
        const s16x8 A0 = *(const s16x8*)apA;
        const s16x8 A1 = *(const s16x8*)(apA + 16);
        const s16x8 A2 = *(const s16x8*)(apA + 32);
        const s16x8 A3 = *(const s16x8*)(apA + 48);
        const s16x8 Aq = *(const s16x8*)(axr + (size_t)(cb0 + q31) * 8);
        const s16x8 C0 = *(const s16x8*)apB;
        const s16x8 C1 = *(const s16x8*)(apB + 16);
        const s16x8 C2 = *(const s16x8*)(apB + 32);
        const s16x8 C3 = *(const s16x8*)(apB + 48);
        const s16x8 Cq = *(const s16x8*)(axr + (size_t)(cb1 + q31) * 8);

        f32x16 accA = {0.f};
        f32x16 accB = {0.f};
        accA = __builtin_amdgcn_mfma_f32_32x32x16_bf16(A0, B0, accA, 0, 0, 0);
        accB = __builtin_amdgcn_mfma_f32_32x32x16_bf16(C0, B0, accB, 0, 0, 0);
        accA = __builtin_amdgcn_mfma_f32_32x32x16_bf16(A1, B1, accA, 0, 0, 0);
        accB = __builtin_amdgcn_mfma_f32_32x32x16_bf16(C1, B1, accB, 0, 0, 0);
        accA = __builtin_amdgcn_mfma_f32_32x32x16_bf16(A2, B2q, accA, 0, 0, 0);
        accB = __builtin_amdgcn_mfma_f32_32x32x16_bf16(C2, B2q, accB, 0, 0, 0);
        accA = __builtin_amdgcn_mfma_f32_32x32x16_bf16(A3, B3, accA, 0, 0, 0);
        accB = __builtin_amdgcn_mfma_f32_32x32x16_bf16(C3, B3, accB, 0, 0, 0);
        accA = __builtin_amdgcn_mfma_f32_32x32x16_bf16(Aq, bs, accA, 0, 0, 0);
        accB = __builtin_amdgcn_mfma_f32_32x32x16_bf16(Cq, bs, accB, 0, 0, 0);
        // acc[r] = sq_c - 2*q.c  for cand c = cb + (r&3) + 8*(r>>2) + hb4

        const unsigned pb0 = (unsigned)(ci * 16);
#pragma unroll
        for (int r = 0; r < 16; ++r) {
            const float s = accA[r];
            unsigned e = (__float_as_uint(s) & ~1023u) | (pb0 + r);
            myqq[myq * 64] = e;            // bank-aligned write
            myq += (s < tau) ? 1 : 0;
        }
        if (__any(myq > QW - 16)) {        // invariant: entry<=23, writes<=38
            for (int i = 0; i < myq; ++i) {
                unsigned e = myqq[i * 64];
                int lo = (int)(e & 1023u);
                int r  = lo & 15;
                int c  = rbase + (lo >> 4) * 32 + (r & 3) + 8 * (r >> 2) + hb4;
                insertL(bd, bi, __uint_as_float(e & ~1023u), c);
            }
            myq = 0;
            tau = bd[LC - 1];
        }

        const unsigned pb1 = pb0 + 16;
#pragma unroll
        for (int r = 0; r < 16; ++r) {
            const float s = accB[r];
            unsigned e = (__float_as_uint(s) & ~1023u) | (pb1 + r);
            myqq[myq * 64] = e;
            myq += (s < tau) ? 1 : 0;
        }
        if (__any(myq > QW - 16)) {
            for (int i = 0; i < myq; ++i) {
                unsigned e = myqq[i * 64];
                int lo = (int)(e & 1023u);
                int r  = lo & 15;
                int c  = rbase + (lo >> 4) * 32 + (r & 3) + 8 * (r >> 2) + hb4;
                insertL(bd, bi, __uint_as_float(e & ~1023u), c);
            }
            myq = 0;
            tau = bd[LC - 1];
        }
    }

    if (__any(myq != 0)) {
        for (int i = 0; i < myq; ++i) {
            unsigned e = myqq[i * 64];
            int lo = (int)(e & 1023u);
            int r  = lo & 15;
            int c  = rbase + (lo >> 4) * 32 + (r & 3) + 8 * (r >> 2) + hb4;
            insertL(bd, bi, __uint_as_float(e & ~1023u), c);
        }
    }

    // write this (virtual-range, query) sorted top-12
    const int vr = range * 2 + hb;         // 0..15 virtual ranges
    float* os = outS + ((size_t)vr * Npts + q) * LC;
    unsigned short* oi = outI + ((size_t)vr * Npts + q) * LC;
#pragma unroll
    for (int k = 0; k < LC; ++k) {
        os[k] = bd[k];
        oi[k] = (unsigned short)bi[k];
    }
}

// ------- k_out: 192 coarse -> top24 (2-phase rank) -> fp64 top10 -> gather-max -------
__global__ __launch_bounds__(192) void k_out(const float* __restrict__ y,
                                             const float* __restrict__ ptsT,
                                             const float* __restrict__ outS,
                                             const unsigned short* __restrict__ outI,
                                             float* __restrict__ out) {
    __shared__ float  sc[NR * LC];
    __shared__ int    ix[NR * LC];
    __shared__ float  s2[96];
    __shared__ int    i2[96];
    __shared__ int    c24[24];
    __shared__ double d2s[24];
    __shared__ int    ci[24];
    __shared__ __align__(16) float qs[Dims];
    __shared__ int    nb[KNN];

    const int n = blockIdx.x;
    const int t = threadIdx.x;

    if (t < Dims) qs[t] = ptsT[(size_t)n * Dims + t];
    {
        const int r = t / LC, k = t - r * LC;   // t < 192 = NR*LC
        sc[t] = outS[((size_t)r * Npts + n) * LC + k];
        ix[t] = (int)outI[((size_t)r * Npts + n) * LC + k];
    }
    __syncthreads();

    // phase 1: rank within group of 48, keep top-24 of each (4 groups -> 96)
    {
        const int gb = (t / 48) * 48;
        const float v = sc[t]; const int vi = ix[t];
        int rk = 0;
        for (int c = 0; c < 48; ++c) {
            float oc = sc[gb + c]; int oi = ix[gb + c];
            rk += (oc < v || (oc == v && oi < vi)) ? 1 : 0;
        }
        if (rk < 24) { s2[(t / 48) * 24 + rk] = v; i2[(t / 48) * 24 + rk] = vi; }
    }
    __syncthreads();

    // phase 2: 96 -> coarse top-24
    if (t < 96) {
        const float v = s2[t]; const int vi = i2[t];
        int rk = 0;
        for (int c = 0; c < 96; ++c)
            rk += (s2[c] < v || (s2[c] == v && i2[c] < vi)) ? 1 : 0;
        if (rk < 24) c24[rk] = vi;
    }
    __syncthreads();

    // exact fp64 d2 for 24 candidates
    if (t < 24) {
        const int j = c24[t];
        double acc = 0.0;
#pragma unroll
        for (int d4 = 0; d4 < Dims / 4; ++d4) {
            const float4 pv = *(const float4*)&ptsT[(size_t)j * Dims + d4 * 4];
            const float4 qv = *(const float4*)&qs[d4 * 4];
            double e0 = (double)qv.x - (double)pv.x;
            double e1 = (double)qv.y - (double)pv.y;
            double e2 = (double)qv.z - (double)pv.z;
            double e3 = (double)qv.w - (double)pv.w;
            acc = fma(e0, e0, acc); acc = fma(e1, e1, acc);
            acc = fma(e2, e2, acc); acc = fma(e3, e3, acc);
        }
        d2s[t] = acc; ci[t] = j;
    }
    __syncthreads();

    // exact top-10 by (d2, idx)
    if (t < 24) {
        const double dv = d2s[t]; const int ji = ci[t];
        int rk = 0;
        for (int c = 0; c < 24; ++c)
            rk += (d2s[c] < dv || (d2s[c] == dv && ci[c] < ji)) ? 1 : 0;
        if (rk < KNN) nb[rk] = ji;
    }
    __syncthreads();

    if (t < Oout) {
        float m = -FLT_MAX;
#pragma unroll
        for (int k = 0; k < KNN; ++k)
            m = fmaxf(m, y[(size_t)nb[k] * Oout + t]);
        out[(size_t)n * Oout + t] = m;
    }
}

// ---------------- launcher ----------------
extern "C" void kernel_launch(void* const* d_in, const int* in_sizes, int n_in,
                              void* d_out, int out_size, void* d_ws, size_t ws_size,
                              hipStream_t stream) {
    const float* x = (const float*)d_in[0];   // (1, 64, 16384)
    const float* W = (const float*)d_in[1];   // (128, 64)
    const float* b = (const float*)d_in[2];   // (128,)
    float* out = (float*)d_out;

    float* ws   = (float*)d_ws;
    float* ptsT = ws;                                        // N*D          (4 MB)
    float* y    = ptsT + (size_t)Npts * Dims;                // N*O          (8 MB)
    unsigned short* xh  = (unsigned short*)(y + (size_t)Npts * Oout); // N*D bf16 (2 MB)
    unsigned short* axh = xh + (size_t)Npts * Dims;          // N*8 bf16     (256 KB)
    float* outS = (float*)(axh + (size_t)Npts * 8);          // NR*N*LC f32  (12 MB)
    unsigned short* outI = (unsigned short*)(outS + (size_t)NR * Npts * LC); // (6 MB)

    k_tr <<<Npts / 64, 256, 0, stream>>>(x, ptsT, xh, axh);
    k_y  <<<Npts / 8, 256, 0, stream>>>(ptsT, W, b, y);
    k_knn<<<1024, 256, 0, stream>>>(xh, axh, outS, outI);
    k_out<<<Npts, 192, 0, stream>>>(y, ptsT, outS, outI, out);
}